// Round 9
// baseline (221.351 us; speedup 1.0000x reference)
//
#include <hip/hip_runtime.h>
#include <math.h>

#define NA 10000
#define NE 40000

typedef float f2 __attribute__((ext_vector_type(2)));
typedef float f4 __attribute__((ext_vector_type(4)));
typedef float f16v __attribute__((ext_vector_type(16)));
typedef int   i4 __attribute__((ext_vector_type(4)));
typedef __bf16 bf16x8 __attribute__((ext_vector_type(8)));

union U8 { unsigned short us[8]; __bf16 b[8]; bf16x8 v; };
union UF4 { f4 v; f2 h[2]; };
union UC16 { f16v v; f2 h[8]; };

static __device__ __forceinline__ unsigned short bf_rne(float x){
  unsigned u = __float_as_uint(x);
  unsigned r = (u + 0x7fffu + ((u>>16)&1u)) >> 16;
  return (unsigned short)r;
}
static __device__ __forceinline__ float bf_to_f(unsigned short h){
  return __uint_as_float(((unsigned)h)<<16);
}
static __device__ __forceinline__ float rcpf(float x){
  float r; asm("v_rcp_f32 %0, %1" : "=v"(r) : "v"(x)); return r;
}
static __device__ __forceinline__ float fsig(float x){
  return rcpf(1.f + __expf(-x));
}
static __device__ __forceinline__ float ftanh(float x){
  float ax = fabsf(x);
  float e = __expf(ax + ax);          // inf for large ax is fine
  float t = 1.f - 2.f*rcpf(e + 1.f);
  return copysignf(t, x);
}
// order-preserving uint encoding of float (for atomicMax); memset-0 acts as -inf
static __device__ __forceinline__ unsigned fenc(float f){
  unsigned b = __float_as_uint(f);
  return (b & 0x80000000u) ? ~b : (b | 0x80000000u);
}
static __device__ __forceinline__ float fdec(unsigned u){
  unsigned b = (u & 0x80000000u) ? (u & 0x7FFFFFFFu) : ~u;
  return __uint_as_float(b);
}

// ---------------- k_pre: fold BN, build MFMA tables, p[a] ----------------
// (cnt histogram dropped: CSR machinery replaced by atomic segmentation)
__global__ __launch_bounds__(256) void k_pre(
  const float* __restrict__ encW, const float* __restrict__ encB,
  const float* __restrict__ eg, const float* __restrict__ ebt,
  const float* __restrict__ e_mn, const float* __restrict__ e_vr,
  const float* __restrict__ attW, const float* __restrict__ attB,
  const float* __restrict__ agm, const float* __restrict__ abt,
  const float* __restrict__ amn, const float* __restrict__ avr,
  const float* __restrict__ wih, const float* __restrict__ whh,
  const float* __restrict__ atom, const float* __restrict__ alW,
  unsigned short* __restrict__ BI,
  unsigned short* __restrict__ aBh, unsigned short* __restrict__ aBl,
  unsigned short* __restrict__ aQh, unsigned short* __restrict__ aQl,
  float* __restrict__ attBf, float* __restrict__ wT,
  float* __restrict__ p)
{
  int tid = threadIdx.x;
  int gid = blockIdx.x*256 + tid;
  int gstride = gridDim.x*256;
  // fused enc B-table, 131072 ush (grid 512*256 covers exactly)
  for (int i=gid; i<131072; i+=gstride){
    int j = i&15, ll = (i>>4)&63, t = i>>10;   // t = d*2+ft
    int d = t>>1, ft = t&1;
    int jj = j&7;
    int k = ((ll>>5)<<3)+jj;
    int n = d*64 + ft*32 + (ll&31);
    float s = eg[n]*rsqrtf(e_vr[n]+1e-6f);
    unsigned short outv = 0;
    if (k<12){
      float wv = encW[n*12+k]*s;
      unsigned short hi = bf_rne(wv);
      outv = (j<8)? hi : bf_rne(wv - bf_to_f(hi));
    } else if (k==12){
      float b = (encB[n]-e_mn[n])*s + ebt[n];
      unsigned short hi = bf_rne(b);
      outv = (j<8)? hi : bf_rne(b - bf_to_f(hi));
    }
    BI[i] = outv;
  }
  // attd B-fragments [kk(4)][nt(2)][lane(64)][j(8)]; B[k][n] = attW[n*64+k]*s_n
  for (int i=gid; i<4096; i+=gstride){
    int j=i&7, l=(i>>3)&63, t=i>>9;
    int kk=t>>1, nt=t&1;
    int k = kk*16 + ((l>>5)<<3) + j;
    int n = nt*32 + (l&31);
    float s = agm[n]*rsqrtf(avr[n]+1e-6f);
    float wv = attW[n*64+k]*s;
    unsigned short hi = bf_rne(wv);
    aBh[i]=hi; aBl[i]=bf_rne(wv - bf_to_f(hi));
  }
  // qv B-fragments [kk(4)][lane(64)][j(8)], masked to consumer lanes em==0
  for (int i=gid; i<2048; i+=gstride){
    int j=i&7, l2=(i>>3)&63, kk=i>>9;
    float v = alW[64 + kk*16 + ((l2>>5)<<3) + j];
    unsigned short hi=0, lo=0;
    if ((l2&31)==0){ hi = bf_rne(v); lo = bf_rne(v - bf_to_f(hi)); }
    aQh[i]=hi; aQl[i]=lo;
  }
  for (int f=gid; f<64; f+=gstride){
    float s = agm[f]*rsqrtf(avr[f]+1e-6f);
    attBf[f] = (attB[f]-amn[f])*s + abt[f];
  }
  // GRU weights [g(6)][kg(16)][f(64)][j(4)]
  for (int i=gid; i<24576; i+=gstride){
    int j=i&3, f=(i>>2)&63, idx2=i>>8;
    int g=idx2>>4, kg=idx2&15, k=kg*4+j;
    wT[i] = (g<3)? wih[(g*64+f)*64+k] : whh[((g-3)*64+f)*64+k];
  }
  // p[a] = alW[0:64] . atom[a]
  {
    int wid = gid>>6;
    int l = tid&63;
    float wl = alW[l];
    for (int a=wid; a<NA; a+=(gstride>>6)){
      float v = wl*atom[(size_t)a*64+l];
      v += __shfl_xor(v,1);  v += __shfl_xor(v,2);
      v += __shfl_xor(v,4);  v += __shfl_xor(v,8);
      v += __shfl_xor(v,16); v += __shfl_xor(v,32);
      if (l==0) p[a]=v;
    }
  }
}

// ---------------- k_edge v12: natural edge order, fused zq + score + atomicMax ----------------
// 32 edges/block, 2 waves, no cross-wave reduce (v11 structure). Epilogue additionally
// computes s = leaky(p[tgt]+qv+alB), stores it to qv[], and atomicMax'es the
// order-preserving uint encoding into mxu[tgt] (segment max without CSR).
__global__ __launch_bounds__(128, 4) void k_edge(
  const float* __restrict__ atom, const int* __restrict__ bidx, const float* __restrict__ bond,
  const unsigned short* __restrict__ BI,
  const unsigned short* __restrict__ aBh, const unsigned short* __restrict__ aBl,
  const unsigned short* __restrict__ aQh, const unsigned short* __restrict__ aQl,
  const float* __restrict__ p, const float* __restrict__ alB,
  float* __restrict__ zC, float* __restrict__ qv, unsigned* __restrict__ mxu)
{
  __shared__ float sA[2304];    // [d(64)][le(32)+4 pad] 9.2KB; reused as sNb[le(32)][68]
  __shared__ int   sTg[32];
  __shared__ int   sNbr[32];

  int tid = threadIdx.x;
  int l = tid & 63;
  int w = tid >> 6;             // 0/1
  int g = l >> 5;
  int em = l & 31;
  int E0 = blockIdx.x * 32;     // 1250 * 32 = 40000

  if (tid < 32){
    int e = E0 + tid;
    sTg[tid]  = bidx[e*2];
    sNbr[tid] = bidx[e*2+1];
  }
  __syncthreads();
  for (int i=tid; i<2048; i+=128){
    int le=i>>6, d=i&63;
    sA[d*36+le] = atom[(size_t)sNbr[le]*64 + d];
  }

  // A fragments (edge = E0+em, natural order -> coalesced bond reads), hi/lo, bias k=12
  U8 A1, A2;
  {
    const f4* bp = (const f4*)(bond + (size_t)(E0+em)*12);
    f4 b0=bp[0], b1v=bp[1], b2v=bp[2];
    float bv[12] = {b0.x,b0.y,b0.z,b0.w,b1v.x,b1v.y,b1v.z,b1v.w,b2v.x,b2v.y,b2v.z,b2v.w};
    #pragma unroll
    for (int j=0;j<8;j++){
      int k = g*8+j;
      float x = (k<12)? bv[k] : (k==12? 1.f : 0.f);
      __bf16 h = (__bf16)x;
      A1.b[j] = h;
      A2.b[j] = (__bf16)(x - (float)h);
    }
  }
  __syncthreads();

  int ft = w;

  f2 nacc[8];
  #pragma unroll
  for (int i=0;i<8;i++) nacc[i] = (f2){0.f,0.f};
  f16v cz;
  #pragma unroll
  for (int r=0;r<16;r++) cz[r] = 0.f;

  // 4-slot / 3-ahead prefetch ring over BI (hi+lo in one 32B line). Over-reads
  // (up to d=66) land in the aB*/aQ* workspace region: pad-safe.
  const bf16x8* pB = (const bf16x8*)BI + ((size_t)ft*64 + l)*2;
  U8 rh[4], rl[4];
  #pragma unroll
  for (int s=0;s<3;s++){ rh[s].v = pB[s*256]; rl[s].v = pB[s*256+1]; }

  #pragma unroll 4
  for (int d=0; d<64; d++){
    int cs = d&3, ns = (d+3)&3;       // compile-time under unroll 4
    rh[ns].v = pB[(size_t)(d+3)*256];
    rl[ns].v = pB[(size_t)(d+3)*256 + 1];

    UF4 ldA[4];
    #pragma unroll
    for (int q=0;q<4;q++) ldA[q].v = *(const f4*)&sA[d*36 + 8*q + 4*g];

    UC16 c;
    c.v = __builtin_amdgcn_mfma_f32_32x32x16_bf16(A1.v, rh[cs].v, cz, 0,0,0);
    c.v = __builtin_amdgcn_mfma_f32_32x32x16_bf16(A2.v, rh[cs].v, c.v, 0,0,0);
    c.v = __builtin_amdgcn_mfma_f32_32x32x16_bf16(A1.v, rl[cs].v, c.v, 0,0,0);
    #pragma unroll
    for (int i=0;i<8;i++){
      f2 ev;
      ev[0] = fmaxf(c.h[i][0], 0.f);
      ev[1] = fmaxf(c.h[i][1], 0.f);
      asm("v_pk_fma_f32 %0, %1, %2, %0"
          : "+v"(nacc[i])
          : "v"(ldA[i>>1].h[i&1]), "v"(ev));
    }
  }

  // hoist epilogue B-fragment loads: latency hides under the sNb write phase below
  int nt = w;
  U8 eBh[4], eBl[4], eQh[4], eQl[4];
  #pragma unroll
  for (int kk=0; kk<4; kk++){
    eBh[kk].v = *(const bf16x8*)(aBh + ((size_t)((kk*2+nt)*64 + l))*8);
    eBl[kk].v = *(const bf16x8*)(aBl + ((size_t)((kk*2+nt)*64 + l))*8);
  }
  if (nt){
    #pragma unroll
    for (int kk=0; kk<4; kk++){
      eQh[kk].v = *(const bf16x8*)(aQh + ((size_t)(kk*64 + l))*8);
      eQl[kk].v = *(const bf16x8*)(aQl + ((size_t)(kk*64 + l))*8);
    }
  }

  // everyone done with sA reads before sNb overwrite (same LDS region)
  __syncthreads();
  {
    #pragma unroll
    for (int r=0;r<16;r++){
      int row = (r&3) + ((r>>2)<<3) + (g<<2);
      sA[row*68 + (ft<<5) + em] = nacc[r>>1][r&1];
    }
  }
  __syncthreads();

  // ---- fused zq epilogue: attd MFMA + qv score + atomicMax segment-max ----
  {
    f16v c, c2;
    #pragma unroll
    for (int r=0;r<16;r++){ c[r] = 0.f; c2[r] = 0.f; }
    #pragma unroll
    for (int kk=0; kk<4; kk++){
      const float* src = &sA[em*68 + kk*16 + g*8];
      f4 x0 = *(const f4*)src;
      f4 x1 = *(const f4*)(src+4);
      U8 Ah, Al;
      #pragma unroll
      for (int j=0;j<4;j++){
        __bf16 h0 = (__bf16)x0[j];
        Ah.b[j] = h0; Al.b[j] = (__bf16)(x0[j] - (float)h0);
        __bf16 h1 = (__bf16)x1[j];
        Ah.b[4+j] = h1; Al.b[4+j] = (__bf16)(x1[j] - (float)h1);
      }
      c = __builtin_amdgcn_mfma_f32_32x32x16_bf16(Ah.v, eBh[kk].v, c, 0,0,0);
      c = __builtin_amdgcn_mfma_f32_32x32x16_bf16(Al.v, eBh[kk].v, c, 0,0,0);
      c = __builtin_amdgcn_mfma_f32_32x32x16_bf16(Ah.v, eBl[kk].v, c, 0,0,0);
      if (nt){
        c2 = __builtin_amdgcn_mfma_f32_32x32x16_bf16(Ah.v, eQh[kk].v, c2, 0,0,0);
        c2 = __builtin_amdgcn_mfma_f32_32x32x16_bf16(Al.v, eQh[kk].v, c2, 0,0,0);
        c2 = __builtin_amdgcn_mfma_f32_32x32x16_bf16(Ah.v, eQl[kk].v, c2, 0,0,0);
      }
    }
    #pragma unroll
    for (int r=0;r<16;r++){
      int row = (r&3) + ((r>>2)<<3) + ((l>>5)<<2);
      zC[(size_t)(E0 + row)*64 + nt*32 + (l&31)] = c[r];
    }
    if (nt && em==0){
      float ab = alB[0];
      #pragma unroll
      for (int r=0;r<16;r++){
        int row = (r&3) + ((r>>2)<<3) + (g<<2);
        int tg = sTg[row];
        float s = p[tg] + c2[r] + ab;
        s = (s>0.f)? s : 0.01f*s;        // leaky_relu -> final score
        qv[E0 + row] = s;
        atomicMax(&mxu[tg], fenc(s));
      }
    }
  }
}

// ---------------- k_acc: edge-parallel exp + atomic scatter (replaces CSR gather) ----------------
// one wave per edge: ex = exp(s - mx[tgt]); y[tgt][f] += ex*zC[e][f]; dn[tgt] += ex.
__global__ __launch_bounds__(256) void k_acc(
  const int* __restrict__ bidx, const float* __restrict__ qv,
  const unsigned* __restrict__ mxu, const float* __restrict__ zC,
  float* __restrict__ y, float* __restrict__ dn)
{
  int e = (blockIdx.x*256 + threadIdx.x) >> 6;
  int l = threadIdx.x & 63;
  if (e < NE){
    int tg = bidx[e*2];
    float mx = fdec(mxu[tg]);
    float ex = __expf(qv[e] - mx);      // in (0,1]
    float zc = zC[(size_t)e*64 + l];
    atomicAdd(&y[(size_t)tg*64 + l], ex*zc);
    if (l==0) atomicAdd(&dn[tg], ex);
  }
}

// ---------------- k_gru v5: direct y/dn read (no CSR, no deg loop) + LDS-staged wT ----------------
__global__ __launch_bounds__(256, 4) void k_gru(
  const float* __restrict__ atom, const float* __restrict__ yv,
  const float* __restrict__ dnv, const float* __restrict__ attBf,
  const float* __restrict__ wT, const float* __restrict__ bih,
  const float* __restrict__ bhh, float* __restrict__ out)
{
  __shared__ float sc[4][4][64];
  __shared__ float shh[4][4][64];
  __shared__ float swT[6144];   // 24KB chunk: [g(6)][kgc(4)][f(64)][j(4)]
  int tid = threadIdx.x;
  int l = tid & 63;
  int w = tid >> 6;
  int base = blockIdx.x*16 + w*4;   // 625*16 = 10000 exactly
  float bias = attBf[l];

  #pragma unroll
  for (int aa=0; aa<4; aa++){
    int a = base + aa;
    float hf = atom[(size_t)a*64 + l];
    float dd = dnv[a];
    float yy = yv[(size_t)a*64 + l];
    float cf = (yy + dd*bias) * rcpf(dd + 1e-8f);   // dd==0 (deg 0) -> cf = 0
    cf = (cf>0.f)? cf : expm1f(cf);
    sc[w][aa][l] = cf; shh[w][aa][l] = hf;
  }

  float acc[6][4];
  #pragma unroll
  for (int gg=0;gg<6;gg++)
    #pragma unroll
    for (int aa=0;aa<4;aa++) acc[gg][aa]=0.f;

  for (int ch=0; ch<4; ch++){
    __syncthreads();
    #pragma unroll
    for (int ii=0; ii<6; ii++){
      int i = tid + ii*256;           // 1536 f4 = 24KB
      int f = i&63, q = i>>6; int gg = q>>2, kgc = q&3;
      ((f4*)swT)[i] = ((const f4*)wT)[(gg*16 + ch*4 + kgc)*64 + f];
    }
    __syncthreads();
    #pragma unroll
    for (int kgc=0; kgc<4; kgc++){
      int kg = ch*4 + kgc;
      f4 wv[6];
      #pragma unroll
      for (int gg=0;gg<6;gg++) wv[gg] = *(const f4*)&swT[((gg*4+kgc)*64 + l)*4];
      #pragma unroll
      for (int aa=0;aa<4;aa++){
        f4 cv = *(const f4*)&sc[w][aa][kg*4];
        f4 hv = *(const f4*)&shh[w][aa][kg*4];
        #pragma unroll
        for (int j=0;j<4;j++){
          acc[0][aa] = fmaf(cv[j], wv[0][j], acc[0][aa]);
          acc[1][aa] = fmaf(cv[j], wv[1][j], acc[1][aa]);
          acc[2][aa] = fmaf(cv[j], wv[2][j], acc[2][aa]);
          acc[3][aa] = fmaf(hv[j], wv[3][j], acc[3][aa]);
          acc[4][aa] = fmaf(hv[j], wv[4][j], acc[4][aa]);
          acc[5][aa] = fmaf(hv[j], wv[5][j], acc[5][aa]);
        }
      }
    }
  }

  float b0 = bih[l], b1 = bih[64+l], b2 = bih[128+l];
  float h0 = bhh[l], h1 = bhh[64+l], h2 = bhh[128+l];
  #pragma unroll
  for (int aa=0;aa<4;aa++){
    int a = base + aa;
    float hf = shh[w][aa][l];
    float r = fsig(acc[0][aa] + b0 + acc[3][aa] + h0);
    float z = fsig(acc[1][aa] + b1 + acc[4][aa] + h1);
    float n = ftanh(acc[2][aa] + b2 + r*(acc[5][aa] + h2));
    out[(size_t)a*64 + l] = (1.f - z)*n + z*hf;
  }
}

extern "C" void kernel_launch(void* const* d_in, const int* in_sizes, int n_in,
                              void* d_out, int out_size, void* d_ws, size_t ws_size,
                              hipStream_t stream) {
  const float* atom = (const float*)d_in[0];
  const int*   bidx = (const int*)  d_in[1];
  const float* bond = (const float*)d_in[2];
  const float* encW = (const float*)d_in[3];
  const float* encB = (const float*)d_in[4];
  const float* eg   = (const float*)d_in[5];
  const float* ebt  = (const float*)d_in[6];
  const float* e_mn = (const float*)d_in[7];
  const float* e_vr = (const float*)d_in[8];
  const float* alW  = (const float*)d_in[9];
  const float* alB  = (const float*)d_in[10];
  const float* atW  = (const float*)d_in[11];
  const float* atB  = (const float*)d_in[12];
  const float* agm  = (const float*)d_in[13];
  const float* abt  = (const float*)d_in[14];
  const float* amn  = (const float*)d_in[15];
  const float* avr  = (const float*)d_in[16];
  const float* wih  = (const float*)d_in[17];
  const float* whh  = (const float*)d_in[18];
  const float* bih  = (const float*)d_in[19];
  const float* bhh  = (const float*)d_in[20];

  float* ws = (float*)d_ws;
  unsigned short* BI  = (unsigned short*)(ws + 0);      // 131072 ush (256KB fused hi/lo table)
  unsigned short* aBh = (unsigned short*)(ws + 65536);  // 4096 ush (also pad for BI over-reads)
  unsigned short* aBl = (unsigned short*)(ws + 67584);  // 4096 ush
  unsigned short* aQh = (unsigned short*)(ws + 69632);  // 2048 ush
  unsigned short* aQl = (unsigned short*)(ws + 70656);  // 2048 ush
  float* attBf   = ws + 71680;    // 64
  float* wT      = ws + 71744;    // 24576
  float* p       = ws + 96320;    // 10016
  unsigned* mxu  = (unsigned*)(ws + 106336);  // 10016 (memset-0 == -inf under fenc)
  float* dn      = ws + 116352;   // 10016
  float* y       = ws + 126368;   // 640000
  float* qv      = ws + 766368;   // 40000
  float* zCb     = ws + 806368;   // 2560000
  float* outp    = (float*)d_out;

  // zero mxu + dn + y in one contiguous memset
  hipMemsetAsync(mxu, 0, (size_t)(10016 + 10016 + 640000)*sizeof(float), stream);
  k_pre<<<512, 256, 0, stream>>>(encW,encB,eg,ebt,e_mn,e_vr,
                                 atW,atB,agm,abt,amn,avr,
                                 wih,whh,atom,alW,
                                 BI,aBh,aBl,aQh,aQl,attBf,wT,p);
  k_edge<<<1250, 128, 0, stream>>>(atom, bidx, bond, BI, aBh, aBl, aQh, aQl,
                                   p, alB, zCb, qv, mxu);
  k_acc<<<10000, 256, 0, stream>>>(bidx, qv, mxu, zCb, y, dn);
  k_gru<<<625, 256, 0, stream>>>(atom, y, dn, attBf, wT, bih, bhh, outp);
}

// Round 10
// 172.113 us; speedup vs baseline: 1.2861x; 1.2861x over previous
//
#include <hip/hip_runtime.h>
#include <math.h>

#define NA 10000
#define NE 40000

typedef float f2 __attribute__((ext_vector_type(2)));
typedef float f4 __attribute__((ext_vector_type(4)));
typedef float f16v __attribute__((ext_vector_type(16)));
typedef int   i4 __attribute__((ext_vector_type(4)));
typedef __bf16 bf16x8 __attribute__((ext_vector_type(8)));

union U8 { unsigned short us[8]; __bf16 b[8]; bf16x8 v; };
union UF4 { f4 v; f2 h[2]; };
union UC16 { f16v v; f2 h[8]; };

static __device__ __forceinline__ unsigned short bf_rne(float x){
  unsigned u = __float_as_uint(x);
  unsigned r = (u + 0x7fffu + ((u>>16)&1u)) >> 16;
  return (unsigned short)r;
}
static __device__ __forceinline__ float bf_to_f(unsigned short h){
  return __uint_as_float(((unsigned)h)<<16);
}
static __device__ __forceinline__ float rcpf(float x){
  float r; asm("v_rcp_f32 %0, %1" : "=v"(r) : "v"(x)); return r;
}
static __device__ __forceinline__ float fsig(float x){
  return rcpf(1.f + __expf(-x));
}
static __device__ __forceinline__ float ftanh(float x){
  float ax = fabsf(x);
  float e = __expf(ax + ax);          // inf for large ax is fine
  float t = 1.f - 2.f*rcpf(e + 1.f);
  return copysignf(t, x);
}

// ---------------- k_pre: fold BN, build MFMA tables, p[a], histogram ----------------
// BI = fused enc B-table: [d(64)][ft(2)][lane(64)][j(16)] ush, j 0..7 = hi frag, 8..15 = lo frag.
// aQh/aQl = pre-masked qv B-fragments (alW[64:128] column, nonzero only for lanes em==0).
__global__ __launch_bounds__(256) void k_pre(
  const float* __restrict__ encW, const float* __restrict__ encB,
  const float* __restrict__ eg, const float* __restrict__ ebt,
  const float* __restrict__ e_mn, const float* __restrict__ e_vr,
  const float* __restrict__ attW, const float* __restrict__ attB,
  const float* __restrict__ agm, const float* __restrict__ abt,
  const float* __restrict__ amn, const float* __restrict__ avr,
  const float* __restrict__ wih, const float* __restrict__ whh,
  const int* __restrict__ bidx, const float* __restrict__ atom,
  const float* __restrict__ alW,
  unsigned short* __restrict__ BI,
  unsigned short* __restrict__ aBh, unsigned short* __restrict__ aBl,
  unsigned short* __restrict__ aQh, unsigned short* __restrict__ aQl,
  float* __restrict__ attBf, float* __restrict__ wT,
  float* __restrict__ p, int* __restrict__ cnt)
{
  int tid = threadIdx.x;
  int gid = blockIdx.x*256 + tid;
  int gstride = gridDim.x*256;
  // fused enc B-table, 131072 ush (grid 512*256 covers exactly)
  for (int i=gid; i<131072; i+=gstride){
    int j = i&15, ll = (i>>4)&63, t = i>>10;   // t = d*2+ft
    int d = t>>1, ft = t&1;
    int jj = j&7;
    int k = ((ll>>5)<<3)+jj;
    int n = d*64 + ft*32 + (ll&31);
    float s = eg[n]*rsqrtf(e_vr[n]+1e-6f);
    unsigned short outv = 0;
    if (k<12){
      float wv = encW[n*12+k]*s;
      unsigned short hi = bf_rne(wv);
      outv = (j<8)? hi : bf_rne(wv - bf_to_f(hi));
    } else if (k==12){
      float b = (encB[n]-e_mn[n])*s + ebt[n];
      unsigned short hi = bf_rne(b);
      outv = (j<8)? hi : bf_rne(b - bf_to_f(hi));
    }
    BI[i] = outv;
  }
  // attd B-fragments [kk(4)][nt(2)][lane(64)][j(8)]; B[k][n] = attW[n*64+k]*s_n
  for (int i=gid; i<4096; i+=gstride){
    int j=i&7, l=(i>>3)&63, t=i>>9;
    int kk=t>>1, nt=t&1;
    int k = kk*16 + ((l>>5)<<3) + j;
    int n = nt*32 + (l&31);
    float s = agm[n]*rsqrtf(avr[n]+1e-6f);
    float wv = attW[n*64+k]*s;
    unsigned short hi = bf_rne(wv);
    aBh[i]=hi; aBl[i]=bf_rne(wv - bf_to_f(hi));
  }
  // qv B-fragments [kk(4)][lane(64)][j(8)], masked to consumer lanes em==0
  for (int i=gid; i<2048; i+=gstride){
    int j=i&7, l2=(i>>3)&63, kk=i>>9;
    float v = alW[64 + kk*16 + ((l2>>5)<<3) + j];
    unsigned short hi=0, lo=0;
    if ((l2&31)==0){ hi = bf_rne(v); lo = bf_rne(v - bf_to_f(hi)); }
    aQh[i]=hi; aQl[i]=lo;
  }
  for (int f=gid; f<64; f+=gstride){
    float s = agm[f]*rsqrtf(avr[f]+1e-6f);
    attBf[f] = (attB[f]-amn[f])*s + abt[f];
  }
  // GRU weights [g(6)][kg(16)][f(64)][j(4)]
  for (int i=gid; i<24576; i+=gstride){
    int j=i&3, f=(i>>2)&63, idx2=i>>8;
    int g=idx2>>4, kg=idx2&15, k=kg*4+j;
    wT[i] = (g<3)? wih[(g*64+f)*64+k] : whh[((g-3)*64+f)*64+k];
  }
  // p[a] = alW[0:64] . atom[a]
  {
    int wid = gid>>6;
    int l = tid&63;
    float wl = alW[l];
    for (int a=wid; a<NA; a+=(gstride>>6)){
      float v = wl*atom[(size_t)a*64+l];
      v += __shfl_xor(v,1);  v += __shfl_xor(v,2);
      v += __shfl_xor(v,4);  v += __shfl_xor(v,8);
      v += __shfl_xor(v,16); v += __shfl_xor(v,32);
      if (l==0) p[a]=v;
    }
  }
  for (int e=gid; e<NE; e+=gstride) atomicAdd(&cnt[bidx[e*2]],1);
}

// ---------------- k_scan ----------------
__global__ __launch_bounds__(256) void k_scan(const int* __restrict__ cnt,
                                              int* __restrict__ rowstart,
                                              int* __restrict__ wofs)
{
  __shared__ int sPart[256];
  int t = threadIdx.x;
  int base = t*40;
  i4 buf[10];
  int sum = 0;
  if (base < NA){
    const i4* cp = (const i4*)(cnt + base);
    #pragma unroll
    for (int i=0;i<10;i++) buf[i] = cp[i];
    #pragma unroll
    for (int i=0;i<10;i++) sum += buf[i].x+buf[i].y+buf[i].z+buf[i].w;
  }
  sPart[t]=sum;
  __syncthreads();
  for (int off=1; off<256; off<<=1){
    int v = (t>=off)? sPart[t-off] : 0;
    __syncthreads();
    sPart[t]+=v;
    __syncthreads();
  }
  int run = sPart[t]-sum;
  if (base < NA){
    #pragma unroll
    for (int i=0;i<10;i++){
      i4 b=buf[i], o;
      o.x=run; run+=b.x; o.y=run; run+=b.y;
      o.z=run; run+=b.z; o.w=run; run+=b.w;
      ((i4*)(rowstart+base))[i]=o;
      ((i4*)(wofs+base))[i]=o;
    }
  }
  if (t==0) rowstart[NA]=NE;
}

// ---------------- k_scatter ----------------
__global__ __launch_bounds__(256) void k_scatter(const int* __restrict__ bidx,
                                                 int* __restrict__ wofs,
                                                 int* __restrict__ elist)
{
  int e = blockIdx.x*256 + threadIdx.x;
  if (e < NE){
    int tg = bidx[e*2];
    int pos = atomicAdd(&wofs[tg],1);
    elist[pos]=e;
  }
}

// ---------------- k_edge v9 (best measured): VALU-lean epilogue ----------------
__global__ __launch_bounds__(256, 3) void k_edge(
  const float* __restrict__ atom, const int* __restrict__ bidx, const float* __restrict__ bond,
  const unsigned short* __restrict__ BI,
  const unsigned short* __restrict__ aBh, const unsigned short* __restrict__ aBl,
  const unsigned short* __restrict__ aQh, const unsigned short* __restrict__ aQl,
  const int* __restrict__ elist, float* __restrict__ zC, float* __restrict__ qv)
{
  __shared__ float sA[4352];    // [d(64)][le(64)+4 pad] 17.4KB; reused as sNb[le][68] in epilogue
  __shared__ float sP[8192];    // partials [dh(2)][ft(2)][t(2)][r(16)][l(64)], 32KB
  __shared__ int   sEl[64];
  __shared__ int   sNbr[64];

  int tid = threadIdx.x;
  int l = tid & 63;
  int w = tid >> 6;
  int g = l >> 5;
  int em = l & 31;
  int E0 = blockIdx.x * 64;     // 625 * 64 = 40000

  if (tid < 64){
    int e = elist[E0+tid];
    sEl[tid] = e;
    sNbr[tid] = bidx[e*2+1];
  }
  __syncthreads();
  for (int i=tid; i<4096; i+=256){
    int le=i>>6, d=i&63;
    sA[d*68+le] = atom[(size_t)sNbr[le]*64 + d];
  }

  // A fragments for both edge tiles (edge = E0 + t*32 + em), hi/lo split, bias slot k=12
  U8 A1[2], A2[2];
  #pragma unroll
  for (int t=0;t<2;t++){
    const f4* bp = (const f4*)(bond + (size_t)sEl[t*32+em]*12);
    f4 b0=bp[0], b1v=bp[1], b2v=bp[2];
    float bv[12] = {b0.x,b0.y,b0.z,b0.w,b1v.x,b1v.y,b1v.z,b1v.w,b2v.x,b2v.y,b2v.z,b2v.w};
    #pragma unroll
    for (int j=0;j<8;j++){
      int k = g*8+j;
      float x = (k<12)? bv[k] : (k==12? 1.f : 0.f);
      __bf16 h = (__bf16)x;
      A1[t].b[j] = h;
      A2[t].b[j] = (__bf16)(x - (float)h);
    }
  }
  __syncthreads();

  int ft = w & 1;
  int dbase = (w >> 1) * 32;

  f2 nacc[2][8];
  #pragma unroll
  for (int t=0;t<2;t++)
    #pragma unroll
    for (int i=0;i<8;i++) nacc[t][i] = (f2){0.f,0.f};
  f16v cz;
  #pragma unroll
  for (int r=0;r<16;r++) cz[r] = 0.f;

  // 4-slot / 3-ahead prefetch ring over BI. Entry (d,ft,lane) = 2 consecutive bf16x8
  // (hi, lo) = one 32B chunk. d-step stride = 2*64*2 = 256 bf16x8 units.
  // Over-reads (up to d=66) land in the aB*/aQ* workspace region: pad-safe.
  const bf16x8* pB = (const bf16x8*)BI + ((size_t)(dbase*2+ft)*64 + l)*2;
  U8 rh[4], rl[4];
  #pragma unroll
  for (int s=0;s<3;s++){ rh[s].v = pB[s*256]; rl[s].v = pB[s*256+1]; }

  #pragma unroll 4
  for (int dd=0; dd<32; dd++){
    int d = dbase + dd;
    int cs = dd&3, ns = (dd+3)&3;     // compile-time under unroll 4
    rh[ns].v = pB[(size_t)(dd+3)*256];
    rl[ns].v = pB[(size_t)(dd+3)*256 + 1];

    UF4 ldA[2][4];
    #pragma unroll
    for (int t=0;t<2;t++)
      #pragma unroll
      for (int q=0;q<4;q++) ldA[t][q].v = *(const f4*)&sA[d*68 + t*32 + 8*q + 4*g];

    #pragma unroll
    for (int t=0;t<2;t++){
      UC16 c;
      c.v = __builtin_amdgcn_mfma_f32_32x32x16_bf16(A1[t].v, rh[cs].v, cz, 0,0,0);
      c.v = __builtin_amdgcn_mfma_f32_32x32x16_bf16(A2[t].v, rh[cs].v, c.v, 0,0,0);
      c.v = __builtin_amdgcn_mfma_f32_32x32x16_bf16(A1[t].v, rl[cs].v, c.v, 0,0,0);
      #pragma unroll
      for (int i=0;i<8;i++){
        f2 ev;
        ev[0] = fmaxf(c.h[i][0], 0.f);
        ev[1] = fmaxf(c.h[i][1], 0.f);
        asm("v_pk_fma_f32 %0, %1, %2, %0"
            : "+v"(nacc[t][i])
            : "v"(ldA[t][i>>1].h[i&1]), "v"(ev));
      }
    }
  }

  // everyone done with sA reads before partial dump / sA reuse
  __syncthreads();
  {
    int dh = w >> 1;
    #pragma unroll
    for (int t=0;t<2;t++)
      #pragma unroll
      for (int r=0;r<16;r++)
        sP[(((dh*2+ft)*2+t)*16 + r)*64 + l] = nacc[t][r>>1][r&1];
  }
  __syncthreads();
  {
    // 4-wave parallel combine: wave w handles (ftw = w&1, tw = w>>1); dh0 + dh1 order preserved
    int ftw = w&1, tw = w>>1;
    #pragma unroll
    for (int r=0;r<16;r++){
      float v = sP[(((0*2+ftw)*2+tw)*16 + r)*64 + l]
              + sP[(((1*2+ftw)*2+tw)*16 + r)*64 + l];
      int m = tw*32 + (r&3) + ((r>>2)<<3) + (g<<2);
      sA[m*68 + (ftw<<5) + em] = v;
    }
  }
  __syncthreads();

  // ---- fused zq epilogue on the 64-edge tile in sA(=sNb) ----
  // All B-fragments loaded upfront (independent -> overlap); kk loop is pure register MFMA.
  {
    int mt2 = w>>1, nt = w&1;
    U8 eBh[4], eBl[4], eQh[4], eQl[4];
    #pragma unroll
    for (int kk=0; kk<4; kk++){
      eBh[kk].v = *(const bf16x8*)(aBh + ((size_t)((kk*2+nt)*64 + l))*8);
      eBl[kk].v = *(const bf16x8*)(aBl + ((size_t)((kk*2+nt)*64 + l))*8);
    }
    if (nt){
      #pragma unroll
      for (int kk=0; kk<4; kk++){
        eQh[kk].v = *(const bf16x8*)(aQh + ((size_t)(kk*64 + l))*8);
        eQl[kk].v = *(const bf16x8*)(aQl + ((size_t)(kk*64 + l))*8);
      }
    }
    f16v c, c2;
    #pragma unroll
    for (int r=0;r<16;r++){ c[r] = 0.f; c2[r] = 0.f; }
    #pragma unroll
    for (int kk=0; kk<4; kk++){
      const float* src = &sA[(mt2*32+em)*68 + kk*16 + g*8];
      f4 x0 = *(const f4*)src;
      f4 x1 = *(const f4*)(src+4);
      U8 Ah, Al;
      #pragma unroll
      for (int j=0;j<4;j++){
        __bf16 h0 = (__bf16)x0[j];
        Ah.b[j] = h0; Al.b[j] = (__bf16)(x0[j] - (float)h0);
        __bf16 h1 = (__bf16)x1[j];
        Ah.b[4+j] = h1; Al.b[4+j] = (__bf16)(x1[j] - (float)h1);
      }
      c = __builtin_amdgcn_mfma_f32_32x32x16_bf16(Ah.v, eBh[kk].v, c, 0,0,0);
      c = __builtin_amdgcn_mfma_f32_32x32x16_bf16(Al.v, eBh[kk].v, c, 0,0,0);
      c = __builtin_amdgcn_mfma_f32_32x32x16_bf16(Ah.v, eBl[kk].v, c, 0,0,0);
      if (nt){
        c2 = __builtin_amdgcn_mfma_f32_32x32x16_bf16(Ah.v, eQh[kk].v, c2, 0,0,0);
        c2 = __builtin_amdgcn_mfma_f32_32x32x16_bf16(Al.v, eQh[kk].v, c2, 0,0,0);
        c2 = __builtin_amdgcn_mfma_f32_32x32x16_bf16(Ah.v, eQl[kk].v, c2, 0,0,0);
      }
    }
    #pragma unroll
    for (int r=0;r<16;r++){
      int row = (r&3) + ((r>>2)<<3) + ((l>>5)<<2);
      zC[(size_t)(E0 + mt2*32 + row)*64 + nt*32 + (l&31)] = c[r];
    }
    if (nt && em==0){
      #pragma unroll
      for (int r=0;r<16;r++){
        int row = (r&3) + ((r>>2)<<3) + (g<<2);
        qv[E0 + mt2*32 + row] = c2[r];
      }
    }
  }
}

// ---------------- k_gru v3: 16 atoms/block (4/wave), LDS-staged wT, fast gates ----------------
__global__ __launch_bounds__(256, 4) void k_gru(
  const float* __restrict__ atom, const float* __restrict__ zC,
  const int* __restrict__ rowstart, const float* __restrict__ p,
  const float* __restrict__ qv, const float* __restrict__ alB,
  const float* __restrict__ attBf, const float* __restrict__ wT,
  const float* __restrict__ bih, const float* __restrict__ bhh,
  float* __restrict__ out)
{
  __shared__ float sc[4][4][64];
  __shared__ float shh[4][4][64];
  __shared__ float swT[6144];   // 24KB chunk: [g(6)][kgc(4)][f(64)][j(4)]
  int tid = threadIdx.x;
  int l = tid & 63;
  int w = tid >> 6;
  int base = blockIdx.x*16 + w*4;   // 625*16 = 10000 exactly
  float bias = attBf[l];
  float ab = alB[0];

  #pragma unroll
  for (int aa=0; aa<4; aa++){
    int a = base + aa;
    float hf = atom[(size_t)a*64 + l];
    float cf = 0.f;
    int d0 = rowstart[a];
    int deg = rowstart[a+1] - d0;
    if (deg > 0){
      float pa = p[a] + ab;
      float mx = -3e38f, dn = 0.f, y = 0.f;
      for (int i=0;i<deg;i++){
        float s = pa + qv[d0+i];
        s = (s>0.f)? s : 0.01f*s;
        float zc = zC[(size_t)(d0+i)*64 + l];
        if (s > mx){
          float al = __expf(mx - s);
          dn *= al; y *= al; mx = s;
        }
        float ex = __expf(s - mx);
        dn += ex;
        y = fmaf(ex, zc, y);
      }
      cf = (y + dn*bias)*rcpf(dn + 1e-8f);
      cf = (cf>0.f)? cf : expm1f(cf);
    }
    sc[w][aa][l] = cf; shh[w][aa][l] = hf;
  }

  float acc[6][4];
  #pragma unroll
  for (int gg=0;gg<6;gg++)
    #pragma unroll
    for (int aa=0;aa<4;aa++) acc[gg][aa]=0.f;

  for (int ch=0; ch<4; ch++){
    __syncthreads();
    #pragma unroll
    for (int ii=0; ii<6; ii++){
      int i = tid + ii*256;           // 1536 f4 = 24KB
      int f = i&63, q = i>>6; int gg = q>>2, kgc = q&3;
      ((f4*)swT)[i] = ((const f4*)wT)[(gg*16 + ch*4 + kgc)*64 + f];
    }
    __syncthreads();
    #pragma unroll
    for (int kgc=0; kgc<4; kgc++){
      int kg = ch*4 + kgc;
      f4 wv[6];
      #pragma unroll
      for (int gg=0;gg<6;gg++) wv[gg] = *(const f4*)&swT[((gg*4+kgc)*64 + l)*4];
      #pragma unroll
      for (int aa=0;aa<4;aa++){
        f4 cv = *(const f4*)&sc[w][aa][kg*4];
        f4 hv = *(const f4*)&shh[w][aa][kg*4];
        #pragma unroll
        for (int j=0;j<4;j++){
          acc[0][aa] = fmaf(cv[j], wv[0][j], acc[0][aa]);
          acc[1][aa] = fmaf(cv[j], wv[1][j], acc[1][aa]);
          acc[2][aa] = fmaf(cv[j], wv[2][j], acc[2][aa]);
          acc[3][aa] = fmaf(hv[j], wv[3][j], acc[3][aa]);
          acc[4][aa] = fmaf(hv[j], wv[4][j], acc[4][aa]);
          acc[5][aa] = fmaf(hv[j], wv[5][j], acc[5][aa]);
        }
      }
    }
  }

  float b0 = bih[l], b1 = bih[64+l], b2 = bih[128+l];
  float h0 = bhh[l], h1 = bhh[64+l], h2 = bhh[128+l];
  #pragma unroll
  for (int aa=0;aa<4;aa++){
    int a = base + aa;
    float hf = shh[w][aa][l];
    float r = fsig(acc[0][aa] + b0 + acc[3][aa] + h0);
    float z = fsig(acc[1][aa] + b1 + acc[4][aa] + h1);
    float n = ftanh(acc[2][aa] + b2 + r*(acc[5][aa] + h2));
    out[(size_t)a*64 + l] = (1.f - z)*n + z*hf;
  }
}

extern "C" void kernel_launch(void* const* d_in, const int* in_sizes, int n_in,
                              void* d_out, int out_size, void* d_ws, size_t ws_size,
                              hipStream_t stream) {
  const float* atom = (const float*)d_in[0];
  const int*   bidx = (const int*)  d_in[1];
  const float* bond = (const float*)d_in[2];
  const float* encW = (const float*)d_in[3];
  const float* encB = (const float*)d_in[4];
  const float* eg   = (const float*)d_in[5];
  const float* ebt  = (const float*)d_in[6];
  const float* e_mn = (const float*)d_in[7];
  const float* e_vr = (const float*)d_in[8];
  const float* alW  = (const float*)d_in[9];
  const float* alB  = (const float*)d_in[10];
  const float* atW  = (const float*)d_in[11];
  const float* atB  = (const float*)d_in[12];
  const float* agm  = (const float*)d_in[13];
  const float* abt  = (const float*)d_in[14];
  const float* amn  = (const float*)d_in[15];
  const float* avr  = (const float*)d_in[16];
  const float* wih  = (const float*)d_in[17];
  const float* whh  = (const float*)d_in[18];
  const float* bih  = (const float*)d_in[19];
  const float* bhh  = (const float*)d_in[20];

  float* ws = (float*)d_ws;
  unsigned short* BI  = (unsigned short*)(ws + 0);      // 131072 ush (256KB fused hi/lo table)
  unsigned short* aBh = (unsigned short*)(ws + 65536);  // 4096 ush (also pad for BI over-reads)
  unsigned short* aBl = (unsigned short*)(ws + 67584);  // 4096 ush
  unsigned short* aQh = (unsigned short*)(ws + 69632);  // 2048 ush
  unsigned short* aQl = (unsigned short*)(ws + 70656);  // 2048 ush
  float* attBf   = ws + 71680;    // 64
  float* wT      = ws + 71744;    // 24576
  float* p       = ws + 96320;    // 10016
  int*   cnt     = (int*)(ws + 106336);   // 10016
  int*   rowstart= (int*)(ws + 116352);   // 10016
  int*   wofs    = (int*)(ws + 126368);   // 10016
  int*   elist   = (int*)(ws + 136384);   // 40000
  float* qv      = ws + 176384;   // 40000
  float* zCb     = ws + 216384;   // 2560000
  float* outp    = (float*)d_out;

  hipMemsetAsync(cnt, 0, NA*sizeof(int), stream);
  k_pre<<<512, 256, 0, stream>>>(encW,encB,eg,ebt,e_mn,e_vr,
                                 atW,atB,agm,abt,amn,avr,
                                 wih,whh,bidx,atom,alW,
                                 BI,aBh,aBl,aQh,aQl,attBf,wT,p,cnt);
  k_scan<<<1, 256, 0, stream>>>(cnt, rowstart, wofs);
  k_scatter<<<(NE+255)/256, 256, 0, stream>>>(bidx, wofs, elist);
  k_edge<<<625, 256, 0, stream>>>(atom, bidx, bond, BI, aBh, aBl, aQh, aQl,
                                  elist, zCb, qv);
  k_gru<<<625, 256, 0, stream>>>(atom, zCb, rowstart, p, qv, alB,
                                 attBf, wT, bih, bhh, outp);
}

// Round 11
// 170.580 us; speedup vs baseline: 1.2976x; 1.0090x over previous
//
#include <hip/hip_runtime.h>
#include <math.h>

#define NA 10000
#define NE 40000

typedef float f2 __attribute__((ext_vector_type(2)));
typedef float f4 __attribute__((ext_vector_type(4)));
typedef float f16v __attribute__((ext_vector_type(16)));
typedef int   i4 __attribute__((ext_vector_type(4)));
typedef __bf16 bf16x8 __attribute__((ext_vector_type(8)));

union U8 { unsigned short us[8]; __bf16 b[8]; bf16x8 v; };
union UF4 { f4 v; f2 h[2]; };
union UC16 { f16v v; f2 h[8]; };

static __device__ __forceinline__ unsigned short bf_rne(float x){
  unsigned u = __float_as_uint(x);
  unsigned r = (u + 0x7fffu + ((u>>16)&1u)) >> 16;
  return (unsigned short)r;
}
static __device__ __forceinline__ float bf_to_f(unsigned short h){
  return __uint_as_float(((unsigned)h)<<16);
}
static __device__ __forceinline__ float rcpf(float x){
  float r; asm("v_rcp_f32 %0, %1" : "=v"(r) : "v"(x)); return r;
}
static __device__ __forceinline__ float fsig(float x){
  return rcpf(1.f + __expf(-x));
}
static __device__ __forceinline__ float ftanh(float x){
  float ax = fabsf(x);
  float e = __expf(ax + ax);          // inf for large ax is fine
  float t = 1.f - 2.f*rcpf(e + 1.f);
  return copysignf(t, x);
}

// ---------------- k_pre: fold BN, build MFMA tables, p[a], histogram ----------------
// BI = fused enc B-table: [d(64)][ft(2)][lane(64)][j(16)] ush, j 0..7 = hi frag, 8..15 = lo frag.
// aQh/aQl = pre-masked qv B-fragments (alW[64:128] column, nonzero only for lanes em==0).
__global__ __launch_bounds__(256) void k_pre(
  const float* __restrict__ encW, const float* __restrict__ encB,
  const float* __restrict__ eg, const float* __restrict__ ebt,
  const float* __restrict__ e_mn, const float* __restrict__ e_vr,
  const float* __restrict__ attW, const float* __restrict__ attB,
  const float* __restrict__ agm, const float* __restrict__ abt,
  const float* __restrict__ amn, const float* __restrict__ avr,
  const float* __restrict__ wih, const float* __restrict__ whh,
  const int* __restrict__ bidx, const float* __restrict__ atom,
  const float* __restrict__ alW,
  unsigned short* __restrict__ BI,
  unsigned short* __restrict__ aBh, unsigned short* __restrict__ aBl,
  unsigned short* __restrict__ aQh, unsigned short* __restrict__ aQl,
  float* __restrict__ attBf, float* __restrict__ wT,
  float* __restrict__ p, int* __restrict__ cnt)
{
  int tid = threadIdx.x;
  int gid = blockIdx.x*256 + tid;
  int gstride = gridDim.x*256;
  // fused enc B-table, 131072 ush (grid 512*256 covers exactly)
  for (int i=gid; i<131072; i+=gstride){
    int j = i&15, ll = (i>>4)&63, t = i>>10;   // t = d*2+ft
    int d = t>>1, ft = t&1;
    int jj = j&7;
    int k = ((ll>>5)<<3)+jj;
    int n = d*64 + ft*32 + (ll&31);
    float s = eg[n]*rsqrtf(e_vr[n]+1e-6f);
    unsigned short outv = 0;
    if (k<12){
      float wv = encW[n*12+k]*s;
      unsigned short hi = bf_rne(wv);
      outv = (j<8)? hi : bf_rne(wv - bf_to_f(hi));
    } else if (k==12){
      float b = (encB[n]-e_mn[n])*s + ebt[n];
      unsigned short hi = bf_rne(b);
      outv = (j<8)? hi : bf_rne(b - bf_to_f(hi));
    }
    BI[i] = outv;
  }
  // attd B-fragments [kk(4)][nt(2)][lane(64)][j(8)]; B[k][n] = attW[n*64+k]*s_n
  for (int i=gid; i<4096; i+=gstride){
    int j=i&7, l=(i>>3)&63, t=i>>9;
    int kk=t>>1, nt=t&1;
    int k = kk*16 + ((l>>5)<<3) + j;
    int n = nt*32 + (l&31);
    float s = agm[n]*rsqrtf(avr[n]+1e-6f);
    float wv = attW[n*64+k]*s;
    unsigned short hi = bf_rne(wv);
    aBh[i]=hi; aBl[i]=bf_rne(wv - bf_to_f(hi));
  }
  // qv B-fragments [kk(4)][lane(64)][j(8)], masked to consumer lanes em==0
  for (int i=gid; i<2048; i+=gstride){
    int j=i&7, l2=(i>>3)&63, kk=i>>9;
    float v = alW[64 + kk*16 + ((l2>>5)<<3) + j];
    unsigned short hi=0, lo=0;
    if ((l2&31)==0){ hi = bf_rne(v); lo = bf_rne(v - bf_to_f(hi)); }
    aQh[i]=hi; aQl[i]=lo;
  }
  for (int f=gid; f<64; f+=gstride){
    float s = agm[f]*rsqrtf(avr[f]+1e-6f);
    attBf[f] = (attB[f]-amn[f])*s + abt[f];
  }
  // GRU weights [g(6)][kg(16)][f(64)][j(4)]
  for (int i=gid; i<24576; i+=gstride){
    int j=i&3, f=(i>>2)&63, idx2=i>>8;
    int g=idx2>>4, kg=idx2&15, k=kg*4+j;
    wT[i] = (g<3)? wih[(g*64+f)*64+k] : whh[((g-3)*64+f)*64+k];
  }
  // p[a] = alW[0:64] . atom[a]
  {
    int wid = gid>>6;
    int l = tid&63;
    float wl = alW[l];
    for (int a=wid; a<NA; a+=(gstride>>6)){
      float v = wl*atom[(size_t)a*64+l];
      v += __shfl_xor(v,1);  v += __shfl_xor(v,2);
      v += __shfl_xor(v,4);  v += __shfl_xor(v,8);
      v += __shfl_xor(v,16); v += __shfl_xor(v,32);
      if (l==0) p[a]=v;
    }
  }
  for (int e=gid; e<NE; e+=gstride) atomicAdd(&cnt[bidx[e*2]],1);
}

// ---------------- k_scan ----------------
__global__ __launch_bounds__(256) void k_scan(const int* __restrict__ cnt,
                                              int* __restrict__ rowstart,
                                              int* __restrict__ wofs)
{
  __shared__ int sPart[256];
  int t = threadIdx.x;
  int base = t*40;
  i4 buf[10];
  int sum = 0;
  if (base < NA){
    const i4* cp = (const i4*)(cnt + base);
    #pragma unroll
    for (int i=0;i<10;i++) buf[i] = cp[i];
    #pragma unroll
    for (int i=0;i<10;i++) sum += buf[i].x+buf[i].y+buf[i].z+buf[i].w;
  }
  sPart[t]=sum;
  __syncthreads();
  for (int off=1; off<256; off<<=1){
    int v = (t>=off)? sPart[t-off] : 0;
    __syncthreads();
    sPart[t]+=v;
    __syncthreads();
  }
  int run = sPart[t]-sum;
  if (base < NA){
    #pragma unroll
    for (int i=0;i<10;i++){
      i4 b=buf[i], o;
      o.x=run; run+=b.x; o.y=run; run+=b.y;
      o.z=run; run+=b.z; o.w=run; run+=b.w;
      ((i4*)(rowstart+base))[i]=o;
      ((i4*)(wofs+base))[i]=o;
    }
  }
  if (t==0) rowstart[NA]=NE;
}

// ---------------- k_scatter ----------------
__global__ __launch_bounds__(256) void k_scatter(const int* __restrict__ bidx,
                                                 int* __restrict__ wofs,
                                                 int* __restrict__ elist)
{
  int e = blockIdx.x*256 + threadIdx.x;
  if (e < NE){
    int tg = bidx[e*2];
    int pos = atomicAdd(&wofs[tg],1);
    elist[pos]=e;
  }
}

// ---------------- k_edge v13: v9 + inline-asm counted-vmcnt prefetch pipeline ----------------
// The HIP compiler defeats source-level prefetch (VGPR stayed 64-76 across all ring variants;
// loads sunk to uses). AITER/HK pattern: asm global_load issued 3 iters ahead, steady-state
// s_waitcnt vmcnt(6) (never 0 in-loop), sched_barrier(0) after each wait (rule #18: hipcc
// hoists register-only MFMA past inline-asm waitcnt), full drain before compiler loads resume.
__global__ __launch_bounds__(256, 3) void k_edge(
  const float* __restrict__ atom, const int* __restrict__ bidx, const float* __restrict__ bond,
  const unsigned short* __restrict__ BI,
  const unsigned short* __restrict__ aBh, const unsigned short* __restrict__ aBl,
  const unsigned short* __restrict__ aQh, const unsigned short* __restrict__ aQl,
  const int* __restrict__ elist, float* __restrict__ zC, float* __restrict__ qv)
{
  __shared__ float sA[4352];    // [d(64)][le(64)+4 pad] 17.4KB; reused as sNb[le][68] in epilogue
  __shared__ float sP[8192];    // partials [dh(2)][ft(2)][t(2)][r(16)][l(64)], 32KB
  __shared__ int   sEl[64];
  __shared__ int   sNbr[64];

  int tid = threadIdx.x;
  int l = tid & 63;
  int w = tid >> 6;
  int g = l >> 5;
  int em = l & 31;
  int E0 = blockIdx.x * 64;     // 625 * 64 = 40000

  if (tid < 64){
    int e = elist[E0+tid];
    sEl[tid] = e;
    sNbr[tid] = bidx[e*2+1];
  }
  __syncthreads();
  for (int i=tid; i<4096; i+=256){
    int le=i>>6, d=i&63;
    sA[d*68+le] = atom[(size_t)sNbr[le]*64 + d];
  }

  // A fragments for both edge tiles (edge = E0 + t*32 + em), hi/lo split, bias slot k=12
  U8 A1[2], A2[2];
  #pragma unroll
  for (int t=0;t<2;t++){
    const f4* bp = (const f4*)(bond + (size_t)sEl[t*32+em]*12);
    f4 b0=bp[0], b1v=bp[1], b2v=bp[2];
    float bv[12] = {b0.x,b0.y,b0.z,b0.w,b1v.x,b1v.y,b1v.z,b1v.w,b2v.x,b2v.y,b2v.z,b2v.w};
    #pragma unroll
    for (int j=0;j<8;j++){
      int k = g*8+j;
      float x = (k<12)? bv[k] : (k==12? 1.f : 0.f);
      __bf16 h = (__bf16)x;
      A1[t].b[j] = h;
      A2[t].b[j] = (__bf16)(x - (float)h);
    }
  }
  __syncthreads();

  int ft = w & 1;
  int dbase = (w >> 1) * 32;

  f2 nacc[2][8];
  #pragma unroll
  for (int t=0;t<2;t++)
    #pragma unroll
    for (int i=0;i<8;i++) nacc[t][i] = (f2){0.f,0.f};
  f16v cz;
  #pragma unroll
  for (int r=0;r<16;r++) cz[r] = 0.f;

  // asm prefetch pipeline over BI. Entry (d,ft,lane) = 32B (hi bf16x8 at +0, lo at +16).
  // d-step stride = 256 bf16x8 units = 4096B. Over-reads (up to d=66) land in the
  // aB*/aQ* workspace region: pad-safe.
  const bf16x8* pB = (const bf16x8*)BI + ((size_t)(dbase*2+ft)*64 + l)*2;
  U8 rh[4], rl[4];
  // prologue: issue 3 pairs (6 loads in flight)
  #pragma unroll
  for (int s=0;s<3;s++){
    const bf16x8* a = pB + (size_t)s*256;
    asm volatile("global_load_dwordx4 %0, %1, off"
                 : "=v"(rh[s].v) : "v"(a));
    asm volatile("global_load_dwordx4 %0, %1, off offset:16"
                 : "=v"(rl[s].v) : "v"(a));
  }

  #pragma unroll 4
  for (int dd=0; dd<32; dd++){
    int d = dbase + dd;
    int cs = dd&3, ns = (dd+3)&3;     // compile-time under unroll 4
    {
      const bf16x8* a = pB + (size_t)(dd+3)*256;
      asm volatile("global_load_dwordx4 %0, %1, off"
                   : "=v"(rh[ns].v) : "v"(a));
      asm volatile("global_load_dwordx4 %0, %1, off offset:16"
                   : "=v"(rl[ns].v) : "v"(a));
    }

    UF4 ldA[2][4];
    #pragma unroll
    for (int t=0;t<2;t++)
      #pragma unroll
      for (int q=0;q<4;q++) ldA[t][q].v = *(const f4*)&sA[d*68 + t*32 + 8*q + 4*g];

    // wait until only the 6 younger loads (pairs dd+1..dd+3) remain in flight:
    // completes pair dd without draining the pipeline.
    asm volatile("s_waitcnt vmcnt(6)" ::: "memory");
    __builtin_amdgcn_sched_barrier(0);

    #pragma unroll
    for (int t=0;t<2;t++){
      UC16 c;
      c.v = __builtin_amdgcn_mfma_f32_32x32x16_bf16(A1[t].v, rh[cs].v, cz, 0,0,0);
      c.v = __builtin_amdgcn_mfma_f32_32x32x16_bf16(A2[t].v, rh[cs].v, c.v, 0,0,0);
      c.v = __builtin_amdgcn_mfma_f32_32x32x16_bf16(A1[t].v, rl[cs].v, c.v, 0,0,0);
      #pragma unroll
      for (int i=0;i<8;i++){
        f2 ev;
        ev[0] = fmaxf(c.h[i][0], 0.f);
        ev[1] = fmaxf(c.h[i][1], 0.f);
        asm("v_pk_fma_f32 %0, %1, %2, %0"
            : "+v"(nacc[t][i])
            : "v"(ldA[t][i>>1].h[i&1]), "v"(ev));
      }
    }
  }
  // drain all asm loads before any compiler-emitted vector-memory ops
  // (compiler's vmcnt bookkeeping doesn't know about ours).
  asm volatile("s_waitcnt vmcnt(0)" ::: "memory");
  __builtin_amdgcn_sched_barrier(0);

  // everyone done with sA reads before partial dump / sA reuse
  __syncthreads();
  {
    int dh = w >> 1;
    #pragma unroll
    for (int t=0;t<2;t++)
      #pragma unroll
      for (int r=0;r<16;r++)
        sP[(((dh*2+ft)*2+t)*16 + r)*64 + l] = nacc[t][r>>1][r&1];
  }
  __syncthreads();
  {
    // 4-wave parallel combine: wave w handles (ftw = w&1, tw = w>>1); dh0 + dh1 order preserved
    int ftw = w&1, tw = w>>1;
    #pragma unroll
    for (int r=0;r<16;r++){
      float v = sP[(((0*2+ftw)*2+tw)*16 + r)*64 + l]
              + sP[(((1*2+ftw)*2+tw)*16 + r)*64 + l];
      int m = tw*32 + (r&3) + ((r>>2)<<3) + (g<<2);
      sA[m*68 + (ftw<<5) + em] = v;
    }
  }
  __syncthreads();

  // ---- fused zq epilogue on the 64-edge tile in sA(=sNb) ----
  // All B-fragments loaded upfront (independent -> overlap); kk loop is pure register MFMA.
  {
    int mt2 = w>>1, nt = w&1;
    U8 eBh[4], eBl[4], eQh[4], eQl[4];
    #pragma unroll
    for (int kk=0; kk<4; kk++){
      eBh[kk].v = *(const bf16x8*)(aBh + ((size_t)((kk*2+nt)*64 + l))*8);
      eBl[kk].v = *(const bf16x8*)(aBl + ((size_t)((kk*2+nt)*64 + l))*8);
    }
    if (nt){
      #pragma unroll
      for (int kk=0; kk<4; kk++){
        eQh[kk].v = *(const bf16x8*)(aQh + ((size_t)(kk*64 + l))*8);
        eQl[kk].v = *(const bf16x8*)(aQl + ((size_t)(kk*64 + l))*8);
      }
    }
    f16v c, c2;
    #pragma unroll
    for (int r=0;r<16;r++){ c[r] = 0.f; c2[r] = 0.f; }
    #pragma unroll
    for (int kk=0; kk<4; kk++){
      const float* src = &sA[(mt2*32+em)*68 + kk*16 + g*8];
      f4 x0 = *(const f4*)src;
      f4 x1 = *(const f4*)(src+4);
      U8 Ah, Al;
      #pragma unroll
      for (int j=0;j<4;j++){
        __bf16 h0 = (__bf16)x0[j];
        Ah.b[j] = h0; Al.b[j] = (__bf16)(x0[j] - (float)h0);
        __bf16 h1 = (__bf16)x1[j];
        Ah.b[4+j] = h1; Al.b[4+j] = (__bf16)(x1[j] - (float)h1);
      }
      c = __builtin_amdgcn_mfma_f32_32x32x16_bf16(Ah.v, eBh[kk].v, c, 0,0,0);
      c = __builtin_amdgcn_mfma_f32_32x32x16_bf16(Al.v, eBh[kk].v, c, 0,0,0);
      c = __builtin_amdgcn_mfma_f32_32x32x16_bf16(Ah.v, eBl[kk].v, c, 0,0,0);
      if (nt){
        c2 = __builtin_amdgcn_mfma_f32_32x32x16_bf16(Ah.v, eQh[kk].v, c2, 0,0,0);
        c2 = __builtin_amdgcn_mfma_f32_32x32x16_bf16(Al.v, eQh[kk].v, c2, 0,0,0);
        c2 = __builtin_amdgcn_mfma_f32_32x32x16_bf16(Ah.v, eQl[kk].v, c2, 0,0,0);
      }
    }
    #pragma unroll
    for (int r=0;r<16;r++){
      int row = (r&3) + ((r>>2)<<3) + ((l>>5)<<2);
      zC[(size_t)(E0 + mt2*32 + row)*64 + nt*32 + (l&31)] = c[r];
    }
    if (nt && em==0){
      #pragma unroll
      for (int r=0;r<16;r++){
        int row = (r&3) + ((r>>2)<<3) + (g<<2);
        qv[E0 + mt2*32 + row] = c2[r];
      }
    }
  }
}

// ---------------- k_gru v3: 16 atoms/block (4/wave), LDS-staged wT, fast gates ----------------
__global__ __launch_bounds__(256, 4) void k_gru(
  const float* __restrict__ atom, const float* __restrict__ zC,
  const int* __restrict__ rowstart, const float* __restrict__ p,
  const float* __restrict__ qv, const float* __restrict__ alB,
  const float* __restrict__ attBf, const float* __restrict__ wT,
  const float* __restrict__ bih, const float* __restrict__ bhh,
  float* __restrict__ out)
{
  __shared__ float sc[4][4][64];
  __shared__ float shh[4][4][64];
  __shared__ float swT[6144];   // 24KB chunk: [g(6)][kgc(4)][f(64)][j(4)]
  int tid = threadIdx.x;
  int l = tid & 63;
  int w = tid >> 6;
  int base = blockIdx.x*16 + w*4;   // 625*16 = 10000 exactly
  float bias = attBf[l];
  float ab = alB[0];

  #pragma unroll
  for (int aa=0; aa<4; aa++){
    int a = base + aa;
    float hf = atom[(size_t)a*64 + l];
    float cf = 0.f;
    int d0 = rowstart[a];
    int deg = rowstart[a+1] - d0;
    if (deg > 0){
      float pa = p[a] + ab;
      float mx = -3e38f, dn = 0.f, y = 0.f;
      for (int i=0;i<deg;i++){
        float s = pa + qv[d0+i];
        s = (s>0.f)? s : 0.01f*s;
        float zc = zC[(size_t)(d0+i)*64 + l];
        if (s > mx){
          float al = __expf(mx - s);
          dn *= al; y *= al; mx = s;
        }
        float ex = __expf(s - mx);
        dn += ex;
        y = fmaf(ex, zc, y);
      }
      cf = (y + dn*bias)*rcpf(dn + 1e-8f);
      cf = (cf>0.f)? cf : expm1f(cf);
    }
    sc[w][aa][l] = cf; shh[w][aa][l] = hf;
  }

  float acc[6][4];
  #pragma unroll
  for (int gg=0;gg<6;gg++)
    #pragma unroll
    for (int aa=0;aa<4;aa++) acc[gg][aa]=0.f;

  for (int ch=0; ch<4; ch++){
    __syncthreads();
    #pragma unroll
    for (int ii=0; ii<6; ii++){
      int i = tid + ii*256;           // 1536 f4 = 24KB
      int f = i&63, q = i>>6; int gg = q>>2, kgc = q&3;
      ((f4*)swT)[i] = ((const f4*)wT)[(gg*16 + ch*4 + kgc)*64 + f];
    }
    __syncthreads();
    #pragma unroll
    for (int kgc=0; kgc<4; kgc++){
      int kg = ch*4 + kgc;
      f4 wv[6];
      #pragma unroll
      for (int gg=0;gg<6;gg++) wv[gg] = *(const f4*)&swT[((gg*4+kgc)*64 + l)*4];
      #pragma unroll
      for (int aa=0;aa<4;aa++){
        f4 cv = *(const f4*)&sc[w][aa][kg*4];
        f4 hv = *(const f4*)&shh[w][aa][kg*4];
        #pragma unroll
        for (int j=0;j<4;j++){
          acc[0][aa] = fmaf(cv[j], wv[0][j], acc[0][aa]);
          acc[1][aa] = fmaf(cv[j], wv[1][j], acc[1][aa]);
          acc[2][aa] = fmaf(cv[j], wv[2][j], acc[2][aa]);
          acc[3][aa] = fmaf(hv[j], wv[3][j], acc[3][aa]);
          acc[4][aa] = fmaf(hv[j], wv[4][j], acc[4][aa]);
          acc[5][aa] = fmaf(hv[j], wv[5][j], acc[5][aa]);
        }
      }
    }
  }

  float b0 = bih[l], b1 = bih[64+l], b2 = bih[128+l];
  float h0 = bhh[l], h1 = bhh[64+l], h2 = bhh[128+l];
  #pragma unroll
  for (int aa=0;aa<4;aa++){
    int a = base + aa;
    float hf = shh[w][aa][l];
    float r = fsig(acc[0][aa] + b0 + acc[3][aa] + h0);
    float z = fsig(acc[1][aa] + b1 + acc[4][aa] + h1);
    float n = ftanh(acc[2][aa] + b2 + r*(acc[5][aa] + h2));
    out[(size_t)a*64 + l] = (1.f - z)*n + z*hf;
  }
}

extern "C" void kernel_launch(void* const* d_in, const int* in_sizes, int n_in,
                              void* d_out, int out_size, void* d_ws, size_t ws_size,
                              hipStream_t stream) {
  const float* atom = (const float*)d_in[0];
  const int*   bidx = (const int*)  d_in[1];
  const float* bond = (const float*)d_in[2];
  const float* encW = (const float*)d_in[3];
  const float* encB = (const float*)d_in[4];
  const float* eg   = (const float*)d_in[5];
  const float* ebt  = (const float*)d_in[6];
  const float* e_mn = (const float*)d_in[7];
  const float* e_vr = (const float*)d_in[8];
  const float* alW  = (const float*)d_in[9];
  const float* alB  = (const float*)d_in[10];
  const float* atW  = (const float*)d_in[11];
  const float* atB  = (const float*)d_in[12];
  const float* agm  = (const float*)d_in[13];
  const float* abt  = (const float*)d_in[14];
  const float* amn  = (const float*)d_in[15];
  const float* avr  = (const float*)d_in[16];
  const float* wih  = (const float*)d_in[17];
  const float* whh  = (const float*)d_in[18];
  const float* bih  = (const float*)d_in[19];
  const float* bhh  = (const float*)d_in[20];

  float* ws = (float*)d_ws;
  unsigned short* BI  = (unsigned short*)(ws + 0);      // 131072 ush (256KB fused hi/lo table)
  unsigned short* aBh = (unsigned short*)(ws + 65536);  // 4096 ush (also pad for BI over-reads)
  unsigned short* aBl = (unsigned short*)(ws + 67584);  // 4096 ush
  unsigned short* aQh = (unsigned short*)(ws + 69632);  // 2048 ush
  unsigned short* aQl = (unsigned short*)(ws + 70656);  // 2048 ush
  float* attBf   = ws + 71680;    // 64
  float* wT      = ws + 71744;    // 24576
  float* p       = ws + 96320;    // 10016
  int*   cnt     = (int*)(ws + 106336);   // 10016
  int*   rowstart= (int*)(ws + 116352);   // 10016
  int*   wofs    = (int*)(ws + 126368);   // 10016
  int*   elist   = (int*)(ws + 136384);   // 40000
  float* qv      = ws + 176384;   // 40000
  float* zCb     = ws + 216384;   // 2560000
  float* outp    = (float*)d_out;

  hipMemsetAsync(cnt, 0, NA*sizeof(int), stream);
  k_pre<<<512, 256, 0, stream>>>(encW,encB,eg,ebt,e_mn,e_vr,
                                 atW,atB,agm,abt,amn,avr,
                                 wih,whh,bidx,atom,alW,
                                 BI,aBh,aBl,aQh,aQl,attBf,wT,p,cnt);
  k_scan<<<1, 256, 0, stream>>>(cnt, rowstart, wofs);
  k_scatter<<<(NE+255)/256, 256, 0, stream>>>(bidx, wofs, elist);
  k_edge<<<625, 256, 0, stream>>>(atom, bidx, bond, BI, aBh, aBl, aQh, aQl,
                                  elist, zCb, qv);
  k_gru<<<625, 256, 0, stream>>>(atom, zCb, rowstart, p, qv, alB,
                                 attBf, wT, bih, bhh, outp);
}